// Round 1
// baseline (487.232 us; speedup 1.0000x reference)
//
#include <hip/hip_runtime.h>

#define DEG 16
#define TT 16
#define MM 8
#define NN 17

#define C_SCALE 14.426950408889634f  /* log2(e)/eps, eps=0.1 */
#define PP (1.0f / 17.0f)
#define QQ 0.125f

__launch_bounds__(256, 1)
__global__ void ltfgw_kernel(const float* __restrict__ x,
                             const int* __restrict__ dstRow,
                             const float* __restrict__ tf,
                             const float* __restrict__ c2g,
                             float* __restrict__ out) {
  __shared__ float4 tf_lds[TT * MM * 16];   // 32 KB: tf[t][m][d] as float4 chunks
  __shared__ float  c2_lds[TT * MM * MM];   // 4 KB
  {
    const float4* tf4g = (const float4*)tf;
    for (int i = threadIdx.x; i < TT * MM * 16; i += 256) tf_lds[i] = tf4g[i];
    for (int i = threadIdx.x; i < TT * MM * MM; i += 256) c2_lds[i] = c2g[i];
  }
  __syncthreads();

  const int gid = blockIdx.x * 256 + (int)threadIdx.x;
  const int node = gid >> 4;
  const int t = gid & (TT - 1);

  // ---------------- Mcost: Mh = 0.5 * Mcost (alpha = 0.5 folded in) ----------------
  float Mh[NN][MM];
  {
    float acc[NN][MM];
    float sq[NN];
#pragma unroll
    for (int r = 0; r < NN; ++r) {
      sq[r] = 0.f;
#pragma unroll
      for (int m = 0; m < MM; ++m) acc[r][m] = 0.f;
    }
    int idxr[NN];
    idxr[0] = node;
#pragma unroll
    for (int r = 1; r < NN; ++r) idxr[r] = dstRow[node * DEG + (r - 1)];

    const float4* x4 = (const float4*)x;
    const float4* tfl = &tf_lds[t * MM * 16];
    for (int c = 0; c < 16; ++c) {       // rolled: keeps code in I-cache
      float4 tfc[MM];
#pragma unroll
      for (int m = 0; m < MM; ++m) tfc[m] = tfl[m * 16 + c];
#pragma unroll
      for (int r = 0; r < NN; ++r) {
        float4 xl = x4[idxr[r] * 16 + c];
        sq[r] += xl.x * xl.x + xl.y * xl.y + xl.z * xl.z + xl.w * xl.w;
#pragma unroll
        for (int m = 0; m < MM; ++m)
          acc[r][m] += xl.x * tfc[m].x + xl.y * tfc[m].y + xl.z * tfc[m].z + xl.w * tfc[m].w;
      }
    }
    // sqT == 1 exactly (templates are L2-normalized along d)
#pragma unroll
    for (int r = 0; r < NN; ++r) {
      float h = 0.5f * (sq[r] + 1.0f);
#pragma unroll
      for (int m = 0; m < MM; ++m) Mh[r][m] = h - acc[r][m];
    }
  }

  const float* c2l = &c2_lds[t * MM * MM];
  // bq[j] = (1/8) * sum_k C2[j][k]^2
  float bq[MM];
#pragma unroll
  for (int j = 0; j < MM; ++j) {
    float s = 0.f;
#pragma unroll
    for (int k = 0; k < MM; ++k) { float v = c2l[j * MM + k]; s += v * v; }
    bq[j] = s * 0.125f;
  }

  // G0 = p q^T (uniform): s = sum_{i>=1} G[i][:], g0 = G[0][:]
  float s_[MM], g0_[MM];
#pragma unroll
  for (int j = 0; j < MM; ++j) { s_[j] = 16.f / 136.f; g0_[j] = 1.f / 136.f; }

  float K[NN][MM];
  float u_[NN], v_[MM], ku[MM];

  for (int outer = 0; outer < 4; ++outer) {
    // tens contributions: cost[i][j] = Mh[i][j] + (i==0 ? T0[j] : T1[j])
    float sc2[MM], gc2[MM];
#pragma unroll
    for (int j = 0; j < MM; ++j) { sc2[j] = 0.f; gc2[j] = 0.f; }
#pragma unroll
    for (int k = 0; k < MM; ++k) {
      float sk = s_[k], gk = g0_[k];
#pragma unroll
      for (int j = 0; j < MM; ++j) {
        float cc = c2l[k * MM + j];
        sc2[j] += sk * cc;
        gc2[j] += gk * cc;
      }
    }
    float T0[MM], T1[MM];
#pragma unroll
    for (int j = 0; j < MM; ++j) {
      T0[j] = 0.5f * (16.f / 17.f + bq[j]) - sc2[j];
      T1[j] = 0.5f * (1.f / 17.f + bq[j]) - gc2[j];
    }
    // cost into K, row shift a0[i] = min_j
#pragma unroll
    for (int i = 0; i < NN; ++i) {
      float a0 = 1e30f;
#pragma unroll
      for (int j = 0; j < MM; ++j) {
        float cij = Mh[i][j] + ((i == 0) ? T0[j] : T1[j]);
        K[i][j] = cij;
        a0 = fminf(a0, cij);
      }
#pragma unroll
      for (int j = 0; j < MM; ++j) K[i][j] -= a0;
    }
    // col shift b0[j] = min_i (cost - a0); then K = exp2((b0 - cs) * C)
    float b0c[MM];
#pragma unroll
    for (int j = 0; j < MM; ++j) {
      float b0 = K[0][j];
#pragma unroll
      for (int i = 1; i < NN; ++i) b0 = fminf(b0, K[i][j]);
      b0c[j] = b0 * C_SCALE;
    }
#pragma unroll
    for (int i = 0; i < NN; ++i)
#pragma unroll
      for (int j = 0; j < MM; ++j)
        K[i][j] = exp2f(b0c[j] - K[i][j] * C_SCALE);

    // stabilized plain Sinkhorn == reference log-domain with f0=g0=0
#pragma unroll
    for (int j = 0; j < MM; ++j) v_[j] = exp2f(-b0c[j]);
    for (int it = 0; it < 10; ++it) {
#pragma unroll
      for (int i = 0; i < NN; ++i) {
        float kv = 0.f;
#pragma unroll
        for (int j = 0; j < MM; ++j) kv += K[i][j] * v_[j];
        u_[i] = PP * __builtin_amdgcn_rcpf(kv);
      }
#pragma unroll
      for (int j = 0; j < MM; ++j) ku[j] = 0.f;
#pragma unroll
      for (int i = 0; i < NN; ++i) {
        float ui = u_[i];
#pragma unroll
        for (int j = 0; j < MM; ++j) ku[j] += K[i][j] * ui;
      }
#pragma unroll
      for (int j = 0; j < MM; ++j) v_[j] = QQ * __builtin_amdgcn_rcpf(ku[j]);
    }
    // G = u K v: marginals for next linearization (reuse last K^T u)
#pragma unroll
    for (int j = 0; j < MM; ++j) {
      float k0u = K[0][j] * u_[0];
      g0_[j] = v_[j] * k0u;
      s_[j]  = v_[j] * (ku[j] - k0u);
    }
  }

  // ---------------- final fgw = sum G4 .* (Mh + 0.5*tens(G4)) ----------------
  float sc2[MM], gc2[MM];
#pragma unroll
  for (int j = 0; j < MM; ++j) { sc2[j] = 0.f; gc2[j] = 0.f; }
#pragma unroll
  for (int k = 0; k < MM; ++k) {
    float sk = s_[k], gk = g0_[k];
#pragma unroll
    for (int j = 0; j < MM; ++j) {
      float cc = c2l[k * MM + j];
      sc2[j] += sk * cc;
      gc2[j] += gk * cc;
    }
  }
  float fg = 0.f;
#pragma unroll
  for (int j = 0; j < MM; ++j) {
    float T0p = 0.5f * (16.f / 17.f + bq[j]) - sc2[j];
    float T1p = 0.5f * (1.f / 17.f + bq[j]) - gc2[j];
    float a2 = 0.f;
#pragma unroll
    for (int i = 1; i < NN; ++i) a2 += (u_[i] * K[i][j]) * Mh[i][j];
    fg += g0_[j] * (Mh[0][j] + T0p) + s_[j] * T1p + v_[j] * a2;
  }
  out[gid] = fg;
}

extern "C" void kernel_launch(void* const* d_in, const int* in_sizes, int n_in,
                              void* d_out, int out_size, void* d_ws, size_t ws_size,
                              hipStream_t stream) {
  const float* x  = (const float*)d_in[0];
  const int*   ei = (const int*)d_in[1];
  const float* tf = (const float*)d_in[2];
  const float* c2 = (const float*)d_in[3];
  const int* dstRow = ei + (in_sizes[1] / 2);  // row 1 of edge_index [2, N*DEG]
  float* out = (float*)d_out;
  int blocks = (out_size + 255) / 256;         // 320000 / 256 = 1250 exact
  ltfgw_kernel<<<blocks, 256, 0, stream>>>(x, dstRow, tf, c2, out);
}

// Round 2
// 427.994 us; speedup vs baseline: 1.1384x; 1.1384x over previous
//
#include <hip/hip_runtime.h>

#define DEG 16
#define TT 16
#define MM 8
#define NN 17

#define C_SCALE 14.426950408889634f  /* log2(e)/eps, eps=0.1 */
#define PP (1.0f / 17.0f)
#define QQ 0.125f

// padded LDS strides (bank-conflict fix):
// tf: per-t row of 128 float4 -> 129 (dword stride 516 % 32 == 4 -> 2-way max, free)
#define TF_STRIDE 129
// c2: per-t row of 64 floats -> 65 (stride % 32 == 1 -> conflict-free)
#define C2_STRIDE 65

__launch_bounds__(256, 1)
__global__ void ltfgw_kernel(const float* __restrict__ x,
                             const int* __restrict__ dstRow,
                             const float* __restrict__ tf,
                             const float* __restrict__ c2g,
                             float* __restrict__ out) {
  __shared__ float4 tf_lds[TT * TF_STRIDE];   // ~33 KB
  __shared__ float  c2_lds[TT * C2_STRIDE];   // ~4.2 KB
  {
    const float4* tf4g = (const float4*)tf;
    for (int i = threadIdx.x; i < TT * MM * 16; i += 256) {
      int tt = i >> 7, rem = i & 127;
      tf_lds[tt * TF_STRIDE + rem] = tf4g[i];
    }
    for (int i = threadIdx.x; i < TT * MM * MM; i += 256) {
      int tt = i >> 6, rem = i & 63;
      c2_lds[tt * C2_STRIDE + rem] = c2g[i];
    }
  }
  __syncthreads();

  const int gid = blockIdx.x * 256 + (int)threadIdx.x;
  const int node = gid >> 4;
  const int t = gid & (TT - 1);

  // ---------------- Mcost: Mh = 0.5 * Mcost (alpha = 0.5 folded in) ----------------
  float Mh[NN][MM];
  {
    float acc[NN][MM];
    float sq[NN];
#pragma unroll
    for (int r = 0; r < NN; ++r) {
      sq[r] = 0.f;
#pragma unroll
      for (int m = 0; m < MM; ++m) acc[r][m] = 0.f;
    }
    int idxr[NN];
    idxr[0] = node;
#pragma unroll
    for (int r = 1; r < NN; ++r) idxr[r] = dstRow[node * DEG + (r - 1)];

    const float4* x4 = (const float4*)x;
    const float4* tfl = &tf_lds[t * TF_STRIDE];
    for (int c = 0; c < 16; ++c) {       // rolled: keeps code in I-cache
      float4 tfc[MM];
#pragma unroll
      for (int m = 0; m < MM; ++m) tfc[m] = tfl[m * 16 + c];
#pragma unroll
      for (int r = 0; r < NN; ++r) {
        float4 xl = x4[idxr[r] * 16 + c];
        sq[r] += xl.x * xl.x + xl.y * xl.y + xl.z * xl.z + xl.w * xl.w;
#pragma unroll
        for (int m = 0; m < MM; ++m)
          acc[r][m] += xl.x * tfc[m].x + xl.y * tfc[m].y + xl.z * tfc[m].z + xl.w * tfc[m].w;
      }
    }
    // sqT == 1 exactly (templates are L2-normalized along d)
#pragma unroll
    for (int r = 0; r < NN; ++r) {
      float h = 0.5f * (sq[r] + 1.0f);
#pragma unroll
      for (int m = 0; m < MM; ++m) Mh[r][m] = h - acc[r][m];
    }
  }

  const float* c2l = &c2_lds[t * C2_STRIDE];
  // bq[j] = (1/8) * sum_k C2[j][k]^2
  float bq[MM];
#pragma unroll
  for (int j = 0; j < MM; ++j) {
    float s = 0.f;
#pragma unroll
    for (int k = 0; k < MM; ++k) { float v = c2l[j * MM + k]; s += v * v; }
    bq[j] = s * 0.125f;
  }

  // G0 = p q^T (uniform): s = sum_{i>=1} G[i][:], g0 = G[0][:]
  float s_[MM], g0_[MM];
#pragma unroll
  for (int j = 0; j < MM; ++j) { s_[j] = 16.f / 136.f; g0_[j] = 1.f / 136.f; }

  float K[NN][MM];
  float u_[NN], v_[MM], ku[MM];

  for (int outer = 0; outer < 4; ++outer) {
    // tens contributions: cost[i][j] = Mh[i][j] + (i==0 ? T0[j] : T1[j])
    float sc2[MM], gc2[MM];
#pragma unroll
    for (int j = 0; j < MM; ++j) { sc2[j] = 0.f; gc2[j] = 0.f; }
#pragma unroll
    for (int k = 0; k < MM; ++k) {
      float sk = s_[k], gk = g0_[k];
#pragma unroll
      for (int j = 0; j < MM; ++j) {
        float cc = c2l[k * MM + j];
        sc2[j] += sk * cc;
        gc2[j] += gk * cc;
      }
    }
    float T0[MM], T1[MM];
#pragma unroll
    for (int j = 0; j < MM; ++j) {
      T0[j] = 0.5f * (16.f / 17.f + bq[j]) - sc2[j];
      T1[j] = 0.5f * (1.f / 17.f + bq[j]) - gc2[j];
    }
    // cost into K, row shift a0[i] = min_j
#pragma unroll
    for (int i = 0; i < NN; ++i) {
      float a0 = 1e30f;
#pragma unroll
      for (int j = 0; j < MM; ++j) {
        float cij = Mh[i][j] + ((i == 0) ? T0[j] : T1[j]);
        K[i][j] = cij;
        a0 = fminf(a0, cij);
      }
#pragma unroll
      for (int j = 0; j < MM; ++j) K[i][j] -= a0;
    }
    // col shift b0[j] = min_i (cost - a0); then K = exp2((b0 - cs) * C)
    float b0c[MM];
#pragma unroll
    for (int j = 0; j < MM; ++j) {
      float b0 = K[0][j];
#pragma unroll
      for (int i = 1; i < NN; ++i) b0 = fminf(b0, K[i][j]);
      b0c[j] = b0 * C_SCALE;
    }
#pragma unroll
    for (int i = 0; i < NN; ++i)
#pragma unroll
      for (int j = 0; j < MM; ++j)
        K[i][j] = __builtin_amdgcn_exp2f(b0c[j] - K[i][j] * C_SCALE);

    // stabilized plain Sinkhorn == reference log-domain with f0=g0=0
#pragma unroll
    for (int j = 0; j < MM; ++j) v_[j] = __builtin_amdgcn_exp2f(-b0c[j]);
    for (int it = 0; it < 10; ++it) {
#pragma unroll
      for (int i = 0; i < NN; ++i) {
        float kv = 0.f;
#pragma unroll
        for (int j = 0; j < MM; ++j) kv += K[i][j] * v_[j];
        u_[i] = PP * __builtin_amdgcn_rcpf(kv);
      }
#pragma unroll
      for (int j = 0; j < MM; ++j) ku[j] = 0.f;
#pragma unroll
      for (int i = 0; i < NN; ++i) {
        float ui = u_[i];
#pragma unroll
        for (int j = 0; j < MM; ++j) ku[j] += K[i][j] * ui;
      }
#pragma unroll
      for (int j = 0; j < MM; ++j) v_[j] = QQ * __builtin_amdgcn_rcpf(ku[j]);
    }
    // G = u K v: marginals for next linearization (reuse last K^T u)
#pragma unroll
    for (int j = 0; j < MM; ++j) {
      float k0u = K[0][j] * u_[0];
      g0_[j] = v_[j] * k0u;
      s_[j]  = v_[j] * (ku[j] - k0u);
    }
  }

  // ---------------- final fgw = sum G4 .* (Mh + 0.5*tens(G4)) ----------------
  float sc2[MM], gc2[MM];
#pragma unroll
  for (int j = 0; j < MM; ++j) { sc2[j] = 0.f; gc2[j] = 0.f; }
#pragma unroll
  for (int k = 0; k < MM; ++k) {
    float sk = s_[k], gk = g0_[k];
#pragma unroll
    for (int j = 0; j < MM; ++j) {
      float cc = c2l[k * MM + j];
      sc2[j] += sk * cc;
      gc2[j] += gk * cc;
    }
  }
  float fg = 0.f;
#pragma unroll
  for (int j = 0; j < MM; ++j) {
    float T0p = 0.5f * (16.f / 17.f + bq[j]) - sc2[j];
    float T1p = 0.5f * (1.f / 17.f + bq[j]) - gc2[j];
    float a2 = 0.f;
#pragma unroll
    for (int i = 1; i < NN; ++i) a2 += (u_[i] * K[i][j]) * Mh[i][j];
    fg += g0_[j] * (Mh[0][j] + T0p) + s_[j] * T1p + v_[j] * a2;
  }
  out[gid] = fg;
}

extern "C" void kernel_launch(void* const* d_in, const int* in_sizes, int n_in,
                              void* d_out, int out_size, void* d_ws, size_t ws_size,
                              hipStream_t stream) {
  const float* x  = (const float*)d_in[0];
  const int*   ei = (const int*)d_in[1];
  const float* tf = (const float*)d_in[2];
  const float* c2 = (const float*)d_in[3];
  const int* dstRow = ei + (in_sizes[1] / 2);  // row 1 of edge_index [2, N*DEG]
  float* out = (float*)d_out;
  int blocks = (out_size + 255) / 256;         // 320000 / 256 = 1250 exact
  ltfgw_kernel<<<blocks, 256, 0, stream>>>(x, dstRow, tf, c2, out);
}

// Round 3
// 406.537 us; speedup vs baseline: 1.1985x; 1.0528x over previous
//
#include <hip/hip_runtime.h>

#define DEG 16
#define TT 16
#define MM 8
#define NN 17

#define C_SCALE 14.426950408889634f  /* log2(e)/eps, eps=0.1 */
#define PP (1.0f / 17.0f)
#define QQ 0.125f

#define TF_STRIDE 129   /* float4 row pad: 516 dwords % 32 == 4 -> 2-way max (free) */
#define C2_STRIDE 65    /* float row pad: 65 % 32 == 1 -> conflict-free */

// ---------------- kernel A: P = x @ tf_flat^T  [n_nodes x 128], sqn = ||x_i||^2 ----
__global__ __launch_bounds__(256) void precomp(const float* __restrict__ x,
                                               const float* __restrict__ tf,
                                               float* __restrict__ P,
                                               float* __restrict__ sqn) {
  __shared__ float4 tf_lds[TT * TF_STRIDE];
  const float4* tf4g = (const float4*)tf;
  for (int i = threadIdx.x; i < TT * MM * 16; i += 256) {
    int tt = i >> 7, rem = i & 127;
    tf_lds[tt * TF_STRIDE + rem] = tf4g[i];
  }
  __syncthreads();

  int gid = blockIdx.x * 256 + (int)threadIdx.x;
  int i = gid >> 4, c = gid & 15;         // node i, template-chunk c (8 cols)
  const float4* x4 = (const float4*)x + (size_t)i * 16;
  const float4* tfl = &tf_lds[c * TF_STRIDE];

  float acc[MM];
  float sq = 0.f;
#pragma unroll
  for (int m = 0; m < MM; ++m) acc[m] = 0.f;
  for (int k = 0; k < 16; ++k) {
    float4 xl = x4[k];
    sq += xl.x * xl.x + xl.y * xl.y + xl.z * xl.z + xl.w * xl.w;
#pragma unroll
    for (int m = 0; m < MM; ++m) {
      float4 tv = tfl[m * 16 + k];
      acc[m] += xl.x * tv.x + xl.y * tv.y + xl.z * tv.z + xl.w * tv.w;
    }
  }
  float4* Pr = (float4*)(P + (size_t)i * 128 + c * 8);
  Pr[0] = make_float4(acc[0], acc[1], acc[2], acc[3]);
  Pr[1] = make_float4(acc[4], acc[5], acc[6], acc[7]);
  if (c == 0) sqn[i] = sq;
}

// ---------------- kernel B: per-(node,template) FGW ----------------
__global__ __launch_bounds__(256, 2) void ltfgw_main(const float* __restrict__ P,
                                                     const float* __restrict__ sqn,
                                                     const int* __restrict__ dstRow,
                                                     const float* __restrict__ c2g,
                                                     float* __restrict__ out) {
  __shared__ float c2_lds[TT * C2_STRIDE];
  for (int i = threadIdx.x; i < TT * MM * MM; i += 256) {
    int tt = i >> 6, rem = i & 63;
    c2_lds[tt * C2_STRIDE + rem] = c2g[i];
  }
  __syncthreads();

  const int gid = blockIdx.x * 256 + (int)threadIdx.x;
  const int node = gid >> 4;
  const int t = gid & 15;
  const float* c2l = &c2_lds[t * C2_STRIDE];

  // bq[j] = (1/8) * sum_k C2[j][k]^2
  float bq[MM];
#pragma unroll
  for (int j = 0; j < MM; ++j) {
    float s = 0.f;
#pragma unroll
    for (int k = 0; k < MM; ++k) { float v = c2l[j * MM + k]; s += v * v; }
    bq[j] = s * 0.125f;
  }

  // gather P rows, build static row-normalized kernel factor E
  float E[NN][MM];
  const float4* Pb = (const float4*)P;
#pragma unroll
  for (int r = 0; r < NN; ++r) {
    int idx = (r == 0) ? node : dstRow[node * DEG + (r - 1)];
    float4 p0 = Pb[(size_t)idx * 32 + t * 2];
    float4 p1 = Pb[(size_t)idx * 32 + t * 2 + 1];
    float pv[MM] = {p0.x, p0.y, p0.z, p0.w, p1.x, p1.y, p1.z, p1.w};
    float pm = pv[0];
#pragma unroll
    for (int j = 1; j < MM; ++j) pm = fmaxf(pm, pv[j]);
#pragma unroll
    for (int j = 0; j < MM; ++j)
      E[r][j] = __builtin_amdgcn_exp2f(C_SCALE * (pv[j] - pm));
  }

  // G0 marginals: s_ = colsum rows>=1, g0_ = row 0
  float s_[MM], g0_[MM];
#pragma unroll
  for (int j = 0; j < MM; ++j) { s_[j] = 16.f / 136.f; g0_[j] = 1.f / 136.f; }

  float u0, u_[16], v_[MM], z[MM], e0c[MM], cf1[MM];

  for (int outer = 0; outer < 4; ++outer) {
    // column offsets T0 (row 0) / T1 (rows >=1) from current marginals
    float sc2[MM], gc2[MM];
#pragma unroll
    for (int j = 0; j < MM; ++j) { sc2[j] = 0.f; gc2[j] = 0.f; }
#pragma unroll
    for (int k = 0; k < MM; ++k) {
      float sk = s_[k], gk = g0_[k];
#pragma unroll
      for (int j = 0; j < MM; ++j) {
        float cc = c2l[k * MM + j];
        sc2[j] += sk * cc;
        gc2[j] += gk * cc;
      }
    }
#pragma unroll
    for (int j = 0; j < MM; ++j) {
      float T0 = 0.5f * (16.f / 17.f + bq[j]) - sc2[j];
      float T1 = 0.5f * (1.f / 17.f + bq[j]) - gc2[j];
      e0c[j] = __builtin_amdgcn_exp2f(-C_SCALE * T0) * E[0][j];  // row-0 kernel row
      cf1[j] = __builtin_amdgcn_exp2f(-C_SCALE * T1);            // col factor rows>=1
      v_[j] = 1.f;   // v0 = exp(g0/eps), g0 = 0
    }
    // plain Sinkhorn on K = [e0c ; E(1:) * cf1], row scalings cancel in G
    for (int it = 0; it < 10; ++it) {
      float w1[MM];
      float kv0 = 0.f;
#pragma unroll
      for (int j = 0; j < MM; ++j) { w1[j] = cf1[j] * v_[j]; kv0 += e0c[j] * v_[j]; }
      u0 = PP * __builtin_amdgcn_rcpf(kv0);
#pragma unroll
      for (int i = 0; i < 16; ++i) {
        float kv = 0.f;
#pragma unroll
        for (int j = 0; j < MM; ++j) kv += E[i + 1][j] * w1[j];
        u_[i] = PP * __builtin_amdgcn_rcpf(kv);
      }
#pragma unroll
      for (int j = 0; j < MM; ++j) z[j] = 0.f;
#pragma unroll
      for (int i = 0; i < 16; ++i) {
        float ui = u_[i];
#pragma unroll
        for (int j = 0; j < MM; ++j) z[j] += E[i + 1][j] * ui;
      }
#pragma unroll
      for (int j = 0; j < MM; ++j) {
        float ku = e0c[j] * u0 + cf1[j] * z[j];
        v_[j] = QQ * __builtin_amdgcn_rcpf(ku);
      }
    }
#pragma unroll
    for (int j = 0; j < MM; ++j) {
      g0_[j] = v_[j] * e0c[j] * u0;          // G row 0
      s_[j]  = v_[j] * cf1[j] * z[j];        // col-sums of G rows >=1
    }
  }

  // ---------------- final fgw = sum G .* (Mh + 0.5*tens(G)) ----------------
  float sc2[MM], gc2[MM];
#pragma unroll
  for (int j = 0; j < MM; ++j) { sc2[j] = 0.f; gc2[j] = 0.f; }
#pragma unroll
  for (int k = 0; k < MM; ++k) {
    float sk = s_[k], gk = g0_[k];
#pragma unroll
    for (int j = 0; j < MM; ++j) {
      float cc = c2l[k * MM + j];
      sc2[j] += sk * cc;
      gc2[j] += gk * cc;
    }
  }
  float T0p[MM], T1p[MM], w1f[MM];
#pragma unroll
  for (int j = 0; j < MM; ++j) {
    T0p[j] = 0.5f * (16.f / 17.f + bq[j]) - sc2[j];
    T1p[j] = 0.5f * (1.f / 17.f + bq[j]) - gc2[j];
    w1f[j] = cf1[j] * v_[j];
  }

  float fg = 0.f;
#pragma unroll
  for (int r = 0; r < NN; ++r) {
    int idx = (r == 0) ? node : dstRow[node * DEG + (r - 1)];
    float4 p0 = Pb[(size_t)idx * 32 + t * 2];
    float4 p1 = Pb[(size_t)idx * 32 + t * 2 + 1];
    float pv[MM] = {p0.x, p0.y, p0.z, p0.w, p1.x, p1.y, p1.z, p1.w};
    float h = 0.5f * (sqn[idx] + 1.0f);      // Mh[r][j] = h - pv[j]
    if (r == 0) {
#pragma unroll
      for (int j = 0; j < MM; ++j) fg += g0_[j] * ((h - pv[j]) + T0p[j]);
    } else {
      float uc = u_[r - 1];
#pragma unroll
      for (int j = 0; j < MM; ++j) fg += (uc * E[r][j]) * w1f[j] * (h - pv[j]);
    }
  }
#pragma unroll
  for (int j = 0; j < MM; ++j) fg += s_[j] * T1p[j];
  out[gid] = fg;
}

extern "C" void kernel_launch(void* const* d_in, const int* in_sizes, int n_in,
                              void* d_out, int out_size, void* d_ws, size_t ws_size,
                              hipStream_t stream) {
  const float* x  = (const float*)d_in[0];
  const int*   ei = (const int*)d_in[1];
  const float* tf = (const float*)d_in[2];
  const float* c2 = (const float*)d_in[3];
  const int* dstRow = ei + (in_sizes[1] / 2);   // row 1 of edge_index [2, N*DEG]
  int n_nodes = in_sizes[0] / 64;               // 20000

  float* P   = (float*)d_ws;                    // [n_nodes][128]
  float* sqn = P + (size_t)n_nodes * 128;       // [n_nodes]
  float* out = (float*)d_out;

  int threadsA = n_nodes * 16;
  precomp<<<(threadsA + 255) / 256, 256, 0, stream>>>(x, tf, P, sqn);
  ltfgw_main<<<(out_size + 255) / 256, 256, 0, stream>>>(P, sqn, dstRow, c2, out);
}

// Round 4
// 382.732 us; speedup vs baseline: 1.2730x; 1.0622x over previous
//
#include <hip/hip_runtime.h>

#define DEG 16
#define TT 16
#define MM 8
#define NNR 8          /* regular rows per lane (lane0: rows 1-8, lane1: rows 9-16) */

#define C_SCALE 14.426950408889634f   /* log2(e)/eps, eps=0.1 */
#define INV_C   0.069314718055994530f /* 1/C_SCALE = eps*ln2 */
#define PP (1.0f / 17.0f)
#define QQ 0.125f

#define TF_STRIDE 129   /* float4 row pad: 516 dwords % 32 == 4 -> 2-way max (free) */
#define C2_STRIDE 65    /* float row pad: 65 % 32 == 1 -> conflict-free */

// ---------------- kernel A: P = x @ tf_flat^T  [n_nodes x 128], sqn = ||x_i||^2 ----
__global__ __launch_bounds__(256) void precomp(const float* __restrict__ x,
                                               const float* __restrict__ tf,
                                               float* __restrict__ P,
                                               float* __restrict__ sqn) {
  __shared__ float4 tf_lds[TT * TF_STRIDE];
  const float4* tf4g = (const float4*)tf;
  for (int i = threadIdx.x; i < TT * MM * 16; i += 256) {
    int tt = i >> 7, rem = i & 127;
    tf_lds[tt * TF_STRIDE + rem] = tf4g[i];
  }
  __syncthreads();

  int gid = blockIdx.x * 256 + (int)threadIdx.x;
  int i = gid >> 4, c = gid & 15;         // node i, template-chunk c (8 cols)
  const float4* x4 = (const float4*)x + (size_t)i * 16;
  const float4* tfl = &tf_lds[c * TF_STRIDE];

  float acc[MM];
  float sq = 0.f;
#pragma unroll
  for (int m = 0; m < MM; ++m) acc[m] = 0.f;
  for (int k = 0; k < 16; ++k) {
    float4 xl = x4[k];
    sq += xl.x * xl.x + xl.y * xl.y + xl.z * xl.z + xl.w * xl.w;
#pragma unroll
    for (int m = 0; m < MM; ++m) {
      float4 tv = tfl[m * 16 + k];
      acc[m] += xl.x * tv.x + xl.y * tv.y + xl.z * tv.z + xl.w * tv.w;
    }
  }
  float4* Pr = (float4*)(P + (size_t)i * 128 + c * 8);
  Pr[0] = make_float4(acc[0], acc[1], acc[2], acc[3]);
  Pr[1] = make_float4(acc[4], acc[5], acc[6], acc[7]);
  if (c == 0) sqn[i] = sq;
}

// ---------------- kernel B: 2 lanes per (node,template) FGW problem ----------------
__global__ __launch_bounds__(256, 2) void ltfgw_main(const float* __restrict__ P,
                                                     const float* __restrict__ sqn,
                                                     const int* __restrict__ dstRow,
                                                     const float* __restrict__ c2g,
                                                     float* __restrict__ out) {
  __shared__ float c2_lds[TT * C2_STRIDE];
  for (int i = threadIdx.x; i < TT * MM * MM; i += 256) {
    int tt = i >> 6, rem = i & 63;
    c2_lds[tt * C2_STRIDE + rem] = c2g[i];
  }
  __syncthreads();

  const int gid = blockIdx.x * 256 + (int)threadIdx.x;
  const int t = gid & 15;
  const int h = (gid >> 4) & 1;           // half: 0 -> rows 0..8, 1 -> rows 9..16
  const int node = gid >> 5;
  const float hmask = (h == 0) ? 1.f : 0.f;
  const float* c2l = &c2_lds[t * C2_STRIDE];

  // bq[j] = (1/8)*sum_k C2[j][k]^2 ; csum[j] = sum_k C2[k][j]
  float bq[MM], csum[MM];
#pragma unroll
  for (int j = 0; j < MM; ++j) {
    float s = 0.f, cs = 0.f;
#pragma unroll
    for (int k = 0; k < MM; ++k) {
      float vjk = c2l[j * MM + k];
      s += vjk * vjk;
      cs += c2l[k * MM + j];
    }
    bq[j] = s * 0.125f;
    csum[j] = cs;
  }

  // ---- gather my rows of P, build row-normalized kernel factor E ----
  const float4* Pb = (const float4*)P;
  const int* nb = dstRow + node * DEG + h * NNR;
  float Ereg[NNR][MM], hp[NNR];
  float E0[MM], hp0;
#pragma unroll
  for (int k = 0; k < NNR; ++k) {
    int idx = nb[k];
    float4 p0 = Pb[(size_t)idx * 32 + t * 2];
    float4 p1 = Pb[(size_t)idx * 32 + t * 2 + 1];
    float pv[MM] = {p0.x, p0.y, p0.z, p0.w, p1.x, p1.y, p1.z, p1.w};
    float pm = pv[0];
#pragma unroll
    for (int j = 1; j < MM; ++j) pm = fmaxf(pm, pv[j]);
#pragma unroll
    for (int j = 0; j < MM; ++j)
      Ereg[k][j] = __builtin_amdgcn_exp2f(C_SCALE * (pv[j] - pm));
    hp[k] = 0.5f * (sqn[idx] + 1.0f) - pm;   // Mh[k][j] = hp[k] - log2(E)/C
  }
  {  // center row (only lane h=0 keeps it; lane1 gets E0 = 0)
    float4 p0 = Pb[(size_t)node * 32 + t * 2];
    float4 p1 = Pb[(size_t)node * 32 + t * 2 + 1];
    float pv[MM] = {p0.x, p0.y, p0.z, p0.w, p1.x, p1.y, p1.z, p1.w};
    float pm = pv[0];
#pragma unroll
    for (int j = 1; j < MM; ++j) pm = fmaxf(pm, pv[j]);
#pragma unroll
    for (int j = 0; j < MM; ++j)
      E0[j] = hmask * __builtin_amdgcn_exp2f(C_SCALE * (pv[j] - pm));
    hp0 = 0.5f * (sqn[node] + 1.0f) - pm;
  }

  // G0 = p q^T: row-0 marginal g0_ ; col-sums of rows>=1 are 0.125 - g0_
  float g0_[MM];
#pragma unroll
  for (int j = 0; j < MM; ++j) g0_[j] = 1.f / 136.f;

  float u0, ureg[NNR], v_[MM], e0c[MM], cf1[MM];

  for (int outer = 0; outer < 4; ++outer) {
    // T0[j] (row0 col offset), T1[j] (rows>=1): one 8x8 matvec on g0_
#pragma unroll
    for (int j = 0; j < MM; ++j) {
      float gd = 0.f;
#pragma unroll
      for (int k = 0; k < MM; ++k) gd += g0_[k] * c2l[k * MM + j];
      float T0 = 0.5f * (16.f / 17.f + bq[j]) - 0.125f * csum[j] + gd;
      float T1 = 0.5f * (1.f / 17.f + bq[j]) - gd;
      e0c[j] = __builtin_amdgcn_exp2f(-C_SCALE * T0) * E0[j];  // lane1: 0
      cf1[j] = __builtin_amdgcn_exp2f(-C_SCALE * T1);
      v_[j] = 1.f;
    }
    // stabilized plain Sinkhorn; lane-pair closes the column reductions
    for (int it = 0; it < 10; ++it) {
      float w1[MM];
      float kv0 = (float)h;                 // lane1: e0c=0 -> kv0=1 -> u0 finite
#pragma unroll
      for (int j = 0; j < MM; ++j) { w1[j] = cf1[j] * v_[j]; kv0 += e0c[j] * v_[j]; }
      u0 = PP * __builtin_amdgcn_rcpf(kv0);
#pragma unroll
      for (int k = 0; k < NNR; ++k) {
        float kv = 0.f;
#pragma unroll
        for (int j = 0; j < MM; ++j) kv += Ereg[k][j] * w1[j];
        ureg[k] = PP * __builtin_amdgcn_rcpf(kv);
      }
      float part[MM];
#pragma unroll
      for (int j = 0; j < MM; ++j) {
        float z = 0.f;
#pragma unroll
        for (int k = 0; k < NNR; ++k) z += Ereg[k][j] * ureg[k];
        part[j] = cf1[j] * z + e0c[j] * u0;
      }
#pragma unroll
      for (int j = 0; j < MM; ++j) {
        float ku = part[j] + __shfl_xor(part[j], 16);
        v_[j] = QQ * __builtin_amdgcn_rcpf(ku);
      }
    }
    // row-0 marginal of G for next linearization (exchange lane0's e0c*u0)
#pragma unroll
    for (int j = 0; j < MM; ++j) {
      float e0u = e0c[j] * u0;              // lane1: 0
      float e0uf = e0u + __shfl_xor(e0u, 16);
      g0_[j] = v_[j] * e0uf;
    }
  }

  // ---------------- final fgw = sum G .* (Mh + 0.5*tens(G)) ----------------
  float fg = 0.f;
  {
    float w1f[MM], T0p[MM], tens1 = 0.f;
#pragma unroll
    for (int j = 0; j < MM; ++j) {
      float gd = 0.f;
#pragma unroll
      for (int k = 0; k < MM; ++k) gd += g0_[k] * c2l[k * MM + j];
      T0p[j] = 0.5f * (16.f / 17.f + bq[j]) - 0.125f * csum[j] + gd;
      float T1p = 0.5f * (1.f / 17.f + bq[j]) - gd;
      tens1 += (0.125f - g0_[j]) * T1p;
      w1f[j] = cf1[j] * v_[j];
    }
    // my regular rows: G[r][j] = ureg*Ereg*w1f ; Mh = hp - log2(E)/C
#pragma unroll
    for (int k = 0; k < NNR; ++k) {
      float racc = 0.f;
#pragma unroll
      for (int j = 0; j < MM; ++j) {
        float e = Ereg[k][j];
        float mh = hp[k] - INV_C * __builtin_amdgcn_logf(fmaxf(e, 1e-30f)) * 1.4426950408889634f;
        racc += e * w1f[j] * mh;
      }
      fg += ureg[k] * racc;
    }
    // lane0-only: center row + structure-constant part over rows>=1
    float r0 = 0.f;
#pragma unroll
    for (int j = 0; j < MM; ++j) {
      float mh0 = hp0 - INV_C * __builtin_amdgcn_logf(fmaxf(E0[j], 1e-30f)) * 1.4426950408889634f;
      r0 += g0_[j] * (mh0 + T0p[j]);
    }
    fg += hmask * (r0 + tens1);
  }
  fg += __shfl_xor(fg, 16);
  if (h == 0) out[node * TT + t] = fg;
}

extern "C" void kernel_launch(void* const* d_in, const int* in_sizes, int n_in,
                              void* d_out, int out_size, void* d_ws, size_t ws_size,
                              hipStream_t stream) {
  const float* x  = (const float*)d_in[0];
  const int*   ei = (const int*)d_in[1];
  const float* tf = (const float*)d_in[2];
  const float* c2 = (const float*)d_in[3];
  const int* dstRow = ei + (in_sizes[1] / 2);   // row 1 of edge_index [2, N*DEG]
  int n_nodes = in_sizes[0] / 64;               // 20000

  float* P   = (float*)d_ws;                    // [n_nodes][128]
  float* sqn = P + (size_t)n_nodes * 128;       // [n_nodes]
  float* out = (float*)d_out;

  int threadsA = n_nodes * 16;
  precomp<<<(threadsA + 255) / 256, 256, 0, stream>>>(x, tf, P, sqn);
  int lanesB = out_size * 2;                    // 2 lanes per problem
  ltfgw_main<<<(lanesB + 255) / 256, 256, 0, stream>>>(P, sqn, dstRow, c2, out);
}

// Round 5
// 363.139 us; speedup vs baseline: 1.3417x; 1.0540x over previous
//
#include <hip/hip_runtime.h>

#define DEG 16
#define TT 16
#define MM 8
#define NNR 8          /* regular rows per lane (lane0: rows 1-8, lane1: rows 9-16) */

#define C_SCALE 14.426950408889634f   /* log2(e)/eps, eps=0.1 */
#define INV_C   0.069314718055994530f /* 1/C_SCALE = eps*ln2 : Mh = hp - INV_C*log2(E) */
#define PP (1.0f / 17.0f)
#define QQ 0.125f

#define TF_STRIDE 129   /* float4 row pad: 516 dwords % 32 == 4 -> 2-way max (free) */
#define C2_STRIDE 65    /* float row pad: 65 % 32 == 1 -> conflict-free */

// ---------------- kernel A: P = x @ tf_flat^T  [n_nodes x 128], sqn = ||x_i||^2 ----
__global__ __launch_bounds__(256) void precomp(const float* __restrict__ x,
                                               const float* __restrict__ tf,
                                               float* __restrict__ P,
                                               float* __restrict__ sqn) {
  __shared__ float4 tf_lds[TT * TF_STRIDE];
  const float4* tf4g = (const float4*)tf;
  for (int i = threadIdx.x; i < TT * MM * 16; i += 256) {
    int tt = i >> 7, rem = i & 127;
    tf_lds[tt * TF_STRIDE + rem] = tf4g[i];
  }
  __syncthreads();

  int gid = blockIdx.x * 256 + (int)threadIdx.x;
  int i = gid >> 4, c = gid & 15;         // node i, template-chunk c (8 cols)
  const float4* x4 = (const float4*)x + (size_t)i * 16;
  const float4* tfl = &tf_lds[c * TF_STRIDE];

  float acc[MM];
  float sq = 0.f;
#pragma unroll
  for (int m = 0; m < MM; ++m) acc[m] = 0.f;
  for (int k = 0; k < 16; ++k) {
    float4 xl = x4[k];
    sq += xl.x * xl.x + xl.y * xl.y + xl.z * xl.z + xl.w * xl.w;
#pragma unroll
    for (int m = 0; m < MM; ++m) {
      float4 tv = tfl[m * 16 + k];
      acc[m] += xl.x * tv.x + xl.y * tv.y + xl.z * tv.z + xl.w * tv.w;
    }
  }
  float4* Pr = (float4*)(P + (size_t)i * 128 + c * 8);
  Pr[0] = make_float4(acc[0], acc[1], acc[2], acc[3]);
  Pr[1] = make_float4(acc[4], acc[5], acc[6], acc[7]);
  if (c == 0) sqn[i] = sq;
}

// ---------------- kernel B: 2 lanes per (node,template) FGW problem ----------------
// waves_per_eu(2,2): pin occupancy target = 2 waves/SIMD so the allocator may use
// up to 256 VGPRs without spilling (launch_bounds(256,2) alone let the heuristic
// target 4 waves/EU -> 128 VGPR + 106 MB scratch spill, round 4).
__global__ __launch_bounds__(256)
__attribute__((amdgpu_waves_per_eu(2, 2)))
void ltfgw_main(const float* __restrict__ P,
                const float* __restrict__ sqn,
                const int* __restrict__ dstRow,
                const float* __restrict__ c2g,
                float* __restrict__ out) {
  __shared__ float c2_lds[TT * C2_STRIDE];
  for (int i = threadIdx.x; i < TT * MM * MM; i += 256) {
    int tt = i >> 6, rem = i & 63;
    c2_lds[tt * C2_STRIDE + rem] = c2g[i];
  }
  __syncthreads();

  const int gid = blockIdx.x * 256 + (int)threadIdx.x;
  const int t = gid & 15;
  const int h = (gid >> 4) & 1;           // half: 0 -> rows 0..8, 1 -> rows 9..16
  const int node = gid >> 5;
  const float hmask = (h == 0) ? 1.f : 0.f;
  const float* c2l = &c2_lds[t * C2_STRIDE];

  // bq[j] = (1/8)*sum_k C2[j][k]^2 ; csum[j] = sum_k C2[k][j]
  float bq[MM], csum[MM];
#pragma unroll
  for (int j = 0; j < MM; ++j) {
    float s = 0.f, cs = 0.f;
#pragma unroll
    for (int k = 0; k < MM; ++k) {
      float vjk = c2l[j * MM + k];
      s += vjk * vjk;
      cs += c2l[k * MM + j];
    }
    bq[j] = s * 0.125f;
    csum[j] = cs;
  }

  // ---- gather my rows of P, build row-normalized kernel factor E ----
  const float4* Pb = (const float4*)P;
  const int* nb = dstRow + node * DEG + h * NNR;
  float Ereg[NNR][MM], hp[NNR];
  float E0[MM], hp0;
#pragma unroll
  for (int k = 0; k < NNR; ++k) {
    int idx = nb[k];
    float4 p0 = Pb[(size_t)idx * 32 + t * 2];
    float4 p1 = Pb[(size_t)idx * 32 + t * 2 + 1];
    float pv[MM] = {p0.x, p0.y, p0.z, p0.w, p1.x, p1.y, p1.z, p1.w};
    float pm = pv[0];
#pragma unroll
    for (int j = 1; j < MM; ++j) pm = fmaxf(pm, pv[j]);
#pragma unroll
    for (int j = 0; j < MM; ++j)
      Ereg[k][j] = __builtin_amdgcn_exp2f(C_SCALE * (pv[j] - pm));
    hp[k] = 0.5f * (sqn[idx] + 1.0f) - pm;   // Mh[k][j] = hp[k] - INV_C*log2(E)
  }
  {  // center row (only lane h=0 keeps it; lane1 gets E0 = 0)
    float4 p0 = Pb[(size_t)node * 32 + t * 2];
    float4 p1 = Pb[(size_t)node * 32 + t * 2 + 1];
    float pv[MM] = {p0.x, p0.y, p0.z, p0.w, p1.x, p1.y, p1.z, p1.w};
    float pm = pv[0];
#pragma unroll
    for (int j = 1; j < MM; ++j) pm = fmaxf(pm, pv[j]);
#pragma unroll
    for (int j = 0; j < MM; ++j)
      E0[j] = hmask * __builtin_amdgcn_exp2f(C_SCALE * (pv[j] - pm));
    hp0 = 0.5f * (sqn[node] + 1.0f) - pm;
  }

  // G0 = p q^T: row-0 marginal g0_ ; col-sums of rows>=1 are 0.125 - g0_
  float g0_[MM];
#pragma unroll
  for (int j = 0; j < MM; ++j) g0_[j] = 1.f / 136.f;

  float u0, ureg[NNR], v_[MM], e0c[MM], cf1[MM];

  for (int outer = 0; outer < 4; ++outer) {
    // T0[j] (row0 col offset), T1[j] (rows>=1): one 8x8 matvec on g0_
#pragma unroll
    for (int j = 0; j < MM; ++j) {
      float gd = 0.f;
#pragma unroll
      for (int k = 0; k < MM; ++k) gd += g0_[k] * c2l[k * MM + j];
      float T0 = 0.5f * (16.f / 17.f + bq[j]) - 0.125f * csum[j] + gd;
      float T1 = 0.5f * (1.f / 17.f + bq[j]) - gd;
      e0c[j] = __builtin_amdgcn_exp2f(-C_SCALE * T0) * E0[j];  // lane1: 0
      cf1[j] = __builtin_amdgcn_exp2f(-C_SCALE * T1);
      v_[j] = 1.f;
    }
    // stabilized plain Sinkhorn; lane-pair closes the column reductions
    for (int it = 0; it < 10; ++it) {
      float w1[MM];
      float kv0 = (float)h;                 // lane1: e0c=0 -> kv0=1 -> u0 finite
#pragma unroll
      for (int j = 0; j < MM; ++j) { w1[j] = cf1[j] * v_[j]; kv0 += e0c[j] * v_[j]; }
      u0 = PP * __builtin_amdgcn_rcpf(kv0);
#pragma unroll
      for (int k = 0; k < NNR; ++k) {
        float kv = 0.f;
#pragma unroll
        for (int j = 0; j < MM; ++j) kv += Ereg[k][j] * w1[j];
        ureg[k] = PP * __builtin_amdgcn_rcpf(kv);
      }
      float part[MM];
#pragma unroll
      for (int j = 0; j < MM; ++j) {
        float z = 0.f;
#pragma unroll
        for (int k = 0; k < NNR; ++k) z += Ereg[k][j] * ureg[k];
        part[j] = cf1[j] * z + e0c[j] * u0;
      }
#pragma unroll
      for (int j = 0; j < MM; ++j) {
        float ku = part[j] + __shfl_xor(part[j], 16);
        v_[j] = QQ * __builtin_amdgcn_rcpf(ku);
      }
    }
    // row-0 marginal of G for next linearization (exchange lane0's e0c*u0)
#pragma unroll
    for (int j = 0; j < MM; ++j) {
      float e0u = e0c[j] * u0;              // lane1: 0
      float e0uf = e0u + __shfl_xor(e0u, 16);
      g0_[j] = v_[j] * e0uf;
    }
  }

  // ---------------- final fgw = sum G .* (Mh + 0.5*tens(G)) ----------------
  float fg = 0.f;
  {
    float w1f[MM], T0p[MM], tens1 = 0.f;
#pragma unroll
    for (int j = 0; j < MM; ++j) {
      float gd = 0.f;
#pragma unroll
      for (int k = 0; k < MM; ++k) gd += g0_[k] * c2l[k * MM + j];
      T0p[j] = 0.5f * (16.f / 17.f + bq[j]) - 0.125f * csum[j] + gd;
      float T1p = 0.5f * (1.f / 17.f + bq[j]) - gd;
      tens1 += (0.125f - g0_[j]) * T1p;
      w1f[j] = cf1[j] * v_[j];
    }
    // my regular rows: G[r][j] = ureg*Ereg*w1f ; Mh = hp - INV_C*log2(E)
#pragma unroll
    for (int k = 0; k < NNR; ++k) {
      float racc = 0.f;
#pragma unroll
      for (int j = 0; j < MM; ++j) {
        float e = Ereg[k][j];
        float mh = hp[k] - INV_C * __builtin_amdgcn_logf(fmaxf(e, 1e-30f));
        racc += e * w1f[j] * mh;
      }
      fg += ureg[k] * racc;
    }
    // lane0-only: center row + structure-constant part over rows>=1
    float r0 = 0.f;
#pragma unroll
    for (int j = 0; j < MM; ++j) {
      float mh0 = hp0 - INV_C * __builtin_amdgcn_logf(fmaxf(E0[j], 1e-30f));
      r0 += g0_[j] * (mh0 + T0p[j]);
    }
    fg += hmask * (r0 + tens1);
  }
  fg += __shfl_xor(fg, 16);
  if (h == 0) out[node * TT + t] = fg;
}

extern "C" void kernel_launch(void* const* d_in, const int* in_sizes, int n_in,
                              void* d_out, int out_size, void* d_ws, size_t ws_size,
                              hipStream_t stream) {
  const float* x  = (const float*)d_in[0];
  const int*   ei = (const int*)d_in[1];
  const float* tf = (const float*)d_in[2];
  const float* c2 = (const float*)d_in[3];
  const int* dstRow = ei + (in_sizes[1] / 2);   // row 1 of edge_index [2, N*DEG]
  int n_nodes = in_sizes[0] / 64;               // 20000

  float* P   = (float*)d_ws;                    // [n_nodes][128]
  float* sqn = P + (size_t)n_nodes * 128;       // [n_nodes]
  float* out = (float*)d_out;

  int threadsA = n_nodes * 16;
  precomp<<<(threadsA + 255) / 256, 256, 0, stream>>>(x, tf, P, sqn);
  int lanesB = out_size * 2;                    // 2 lanes per problem
  ltfgw_main<<<(lanesB + 255) / 256, 256, 0, stream>>>(P, sqn, dstRow, c2, out);
}